// Round 9
// baseline (860.419 us; speedup 1.0000x reference)
//
#include <hip/hip_runtime.h>
#include <math.h>

#define N_NODES 50000
#define N_EDGES 300000
#define IN_DIM 64
#define H 256
#define LAYERS 4
#define NB 181
#define NGRAPH 64
#define EE (N_EDGES + N_NODES)
#define NEG_SLOPE 0.2f
#define LN_EPS 1e-5f

typedef unsigned short u16;
typedef __attribute__((ext_vector_type(8))) _Float16 half8;
typedef __attribute__((ext_vector_type(2))) _Float16 half2v;
typedef __attribute__((ext_vector_type(4))) float floatx4;

__device__ __forceinline__ u16 f2h(float f) {
  _Float16 h = (_Float16)f;
  return __builtin_bit_cast(u16, h);
}
__device__ __forceinline__ float h2f(u16 b) {
  return (float)__builtin_bit_cast(_Float16, b);
}

__device__ __forceinline__ float wave_reduce_sum(float v) {
  #pragma unroll
  for (int off = 32; off > 0; off >>= 1) v += __shfl_xor(v, off, 64);
  return v;
}

// ---------------- casts ----------------
__global__ void cast_f16_kernel(const float* __restrict__ in, u16* __restrict__ out, int n4) {
  int i = blockIdx.x * 256 + threadIdx.x;
  if (i < n4) {
    float4 f = ((const float4*)in)[i];
    ushort4 o;
    o.x = f2h(f.x); o.y = f2h(f.y); o.z = f2h(f.z); o.w = f2h(f.w);
    ((ushort4*)out)[i] = o;
  }
}

// all weight casts in one launch (blockIdx.y selects tensor; 4 = att)
__global__ void cast_weights_kernel(
    const float* __restrict__ W_in, const float* __restrict__ Wg1,
    const float* __restrict__ Wl, const float* __restrict__ Wr,
    const float* __restrict__ att,
    u16* __restrict__ win_h, u16* __restrict__ wg1_h,
    u16* __restrict__ wl_h, u16* __restrict__ wr_h,
    u16* __restrict__ att_h)
{
  int i = blockIdx.x * 256 + threadIdx.x;
  int which = blockIdx.y;
  const float* s; u16* dd; int n4;
  if (which == 0)      { s = W_in; dd = win_h; n4 = H * IN_DIM / 4; }
  else if (which == 1) { s = Wg1;  dd = wg1_h; n4 = H * H / 4; }
  else if (which == 2) { s = Wl;   dd = wl_h;  n4 = LAYERS * H * H / 4; }
  else if (which == 3) { s = Wr;   dd = wr_h;  n4 = LAYERS * H * H / 4; }
  else                 { s = att;  dd = att_h; n4 = LAYERS * H / 4; }
  if (i < n4) {
    float4 f = ((const float4*)s)[i];
    ushort4 o;
    o.x = f2h(f.x); o.y = f2h(f.y); o.z = f2h(f.z); o.w = f2h(f.w);
    ((ushort4*)dd)[i] = o;
  }
}

// ---------------- CSR build ----------------
__global__ void init_counts_kernel(int* __restrict__ cnt) {
  int i = blockIdx.x * 256 + threadIdx.x;
  if (i < N_NODES) cnt[i] = 1;  // self loop
}

__global__ void count_edges_kernel(const int* __restrict__ dst, int* __restrict__ cnt) {
  int e = blockIdx.x * 256 + threadIdx.x;
  if (e < N_EDGES) atomicAdd(&cnt[dst[e]], 1);
}

__global__ void scan_blocks_kernel(const int* __restrict__ cnt, int* __restrict__ partial,
                                   int* __restrict__ bsums, int n) {
  __shared__ int buf[256];
  int tid = threadIdx.x;
  int i = blockIdx.x * 256 + tid;
  buf[tid] = (i < n) ? cnt[i] : 0;
  __syncthreads();
  #pragma unroll
  for (int off = 1; off < 256; off <<= 1) {
    int t = (tid >= off) ? buf[tid - off] : 0;
    __syncthreads();
    buf[tid] += t;
    __syncthreads();
  }
  if (i < n) partial[i] = buf[tid];
  if (tid == 255) bsums[blockIdx.x] = buf[255];
}

__global__ void scan_sums_kernel(int* __restrict__ bsums, int nblk) {
  __shared__ int buf[256];
  int tid = threadIdx.x;
  buf[tid] = (tid < nblk) ? bsums[tid] : 0;
  __syncthreads();
  #pragma unroll
  for (int off = 1; off < 256; off <<= 1) {
    int t = (tid >= off) ? buf[tid - off] : 0;
    __syncthreads();
    buf[tid] += t;
    __syncthreads();
  }
  if (tid < nblk) bsums[tid] = buf[tid];
}

__global__ void scan_write_kernel(const int* __restrict__ partial, const int* __restrict__ bsums,
                                  int* __restrict__ rowp, int n) {
  int i = blockIdx.x * 256 + threadIdx.x;
  if (i < n) {
    int b = blockIdx.x;
    int off = (b > 0) ? bsums[b - 1] : 0;
    rowp[i + 1] = partial[i] + off;
    if (i == 0) rowp[0] = 0;
  }
}

__global__ void fill_self_kernel(const int* __restrict__ rowp, int* __restrict__ col,
                                 int* __restrict__ rowdst, int* __restrict__ fillpos) {
  int i = blockIdx.x * 256 + threadIdx.x;
  if (i < N_NODES) {
    int p = rowp[i];
    col[p] = i;
    rowdst[p] = i;
    fillpos[i] = p + 1;
  }
}

__global__ void fill_edges_kernel(const int* __restrict__ src, const int* __restrict__ dst,
                                  int* __restrict__ fillpos, int* __restrict__ col,
                                  int* __restrict__ rowdst) {
  int e = blockIdx.x * 256 + threadIdx.x;
  if (e < N_EDGES) {
    int d = dst[e];
    int p = atomicAdd(&fillpos[d], 1);
    col[p] = src[e];
    rowdst[p] = d;
  }
}

// ---------------- MFMA GEMM tiles ----------------
#define GTM 128
#define GTK 64
#define LDB 72
#define SSTR 132

__global__ __launch_bounds__(256) void gemm_proj_kernel(
    const u16* __restrict__ A, const u16* __restrict__ W,
    const float* __restrict__ bias, u16* __restrict__ outh, int M, int K)
{
  __shared__ u16 smem[2 * GTM * LDB];
  u16* As = smem;
  u16* Bs = smem + GTM * LDB;
  int tid = threadIdx.x;
  int lane = tid & 63;
  int wave = tid >> 6;
  int wm = (wave >> 1) * 64;
  int wn = (wave & 1) * 64;
  int bm = blockIdx.y * GTM;
  int n0 = blockIdx.x * 128;
  int lr = tid >> 3;
  int lc = (tid & 7) * 8;

  floatx4 zero4 = {0.f, 0.f, 0.f, 0.f};
  floatx4 acc[4][4];
  #pragma unroll
  for (int i = 0; i < 4; i++)
    #pragma unroll
    for (int j = 0; j < 4; j++) acc[i][j] = zero4;

  int q8 = (lane >> 4) * 8;
  int mrow = lane & 15;

  for (int k0 = 0; k0 < K; k0 += GTK) {
    __syncthreads();
    #pragma unroll
    for (int p = 0; p < 4; p++) {
      int row = lr + p * 32;
      int gr = bm + row;
      uint4 av = {0, 0, 0, 0};
      if (gr < M) av = *(const uint4*)&A[(size_t)gr * K + k0 + lc];
      *(uint4*)&As[row * LDB + lc] = av;
      uint4 bv = *(const uint4*)&W[(size_t)(n0 + row) * K + k0 + lc];
      *(uint4*)&Bs[row * LDB + lc] = bv;
    }
    __syncthreads();
    #pragma unroll
    for (int h = 0; h < 2; h++) {
      half8 af[4], bf[4];
      #pragma unroll
      for (int i = 0; i < 4; i++)
        af[i] = *(const half8*)&As[(wm + i * 16 + mrow) * LDB + h * 32 + q8];
      #pragma unroll
      for (int j = 0; j < 4; j++)
        bf[j] = *(const half8*)&Bs[(wn + j * 16 + mrow) * LDB + h * 32 + q8];
      #pragma unroll
      for (int i = 0; i < 4; i++)
        #pragma unroll
        for (int j = 0; j < 4; j++)
          acc[i][j] = __builtin_amdgcn_mfma_f32_16x16x32_f16(af[i], bf[j], acc[i][j], 0, 0, 0);
    }
  }

  __syncthreads();
  u16* stage = smem;
  int ccol = lane & 15;
  int crow4 = (lane >> 4) * 4;
  #pragma unroll
  for (int j = 0; j < 4; j++) {
    float bv = bias[n0 + wn + j * 16 + ccol];
    #pragma unroll
    for (int i = 0; i < 4; i++) {
      #pragma unroll
      for (int r = 0; r < 4; r++) {
        int row = wm + i * 16 + crow4 + r;
        stage[row * SSTR + wn + j * 16 + ccol] = f2h(acc[i][j][r] + bv);
      }
    }
  }
  __syncthreads();
  int rr = tid >> 1;
  int c0 = (tid & 1) * 64;
  int grow = bm + rr;
  if (grow < M) {
    const ushort4* sp = (const ushort4*)&stage[rr * SSTR + c0];
    ushort4* gp = (ushort4*)&outh[(size_t)grow * H + n0 + c0];
    #pragma unroll
    for (int q = 0; q < 16; q++) gp[q] = sp[q];
  }
}

// ---------------- dual GEMM v2: A-resident in LDS, 64-row m-tiles ----------------
#define DTM 64
#define AST 264
#define SSTR2 132

__global__ __launch_bounds__(256) void gemm_dual2_kernel(
    const u16* __restrict__ A, const u16* __restrict__ Wlb, const u16* __restrict__ Wrb,
    const float* __restrict__ biasL, const float* __restrict__ biasR,
    u16* __restrict__ outL, u16* __restrict__ outR, int M)
{
  __shared__ u16 As[DTM * AST];
  __shared__ u16 Bs[128 * LDB];
  int tid = threadIdx.x;
  int lane = tid & 63;
  int wave = tid >> 6;
  int wn = wave * 32;
  int bm = blockIdx.x * DTM;
  int mrow = lane & 15;
  int q8 = (lane >> 4) * 8;
  int ccol = lane & 15;
  int crow4 = (lane >> 4) * 4;

  {
    int col = (tid & 31) * 8;
    int r0 = tid >> 5;
    #pragma unroll
    for (int it = 0; it < 8; it++) {
      int row = r0 + it * 8;
      int gr = bm + row;
      uint4 av = {0, 0, 0, 0};
      if (gr < M) av = *(const uint4*)&A[(size_t)gr * H + col];
      *(uint4*)&As[row * AST + col] = av;
    }
  }

  floatx4 zero4 = {0.f, 0.f, 0.f, 0.f};

  for (int nt = 0; nt < 4; nt++) {
    const u16* W = (nt < 2) ? Wlb : Wrb;
    const float* bias = (nt < 2) ? biasL : biasR;
    u16* outp = (nt < 2) ? outL : outR;
    int n0 = (nt & 1) * 128;

    floatx4 acc[4][2];
    #pragma unroll
    for (int i = 0; i < 4; i++) {
      acc[i][0] = zero4;
      acc[i][1] = zero4;
    }

    for (int k0 = 0; k0 < H; k0 += 64) {
      __syncthreads();
      {
        int col = (tid & 7) * 8;
        int r0 = tid >> 3;
        #pragma unroll
        for (int p2 = 0; p2 < 4; p2++) {
          int row = r0 + p2 * 32;
          uint4 bv = *(const uint4*)&W[(size_t)(n0 + row) * H + k0 + col];
          *(uint4*)&Bs[row * LDB + col] = bv;
        }
      }
      __syncthreads();
      #pragma unroll
      for (int h = 0; h < 2; h++) {
        half8 af[4], bf[2];
        #pragma unroll
        for (int i = 0; i < 4; i++)
          af[i] = *(const half8*)&As[(i * 16 + mrow) * AST + k0 + h * 32 + q8];
        #pragma unroll
        for (int j = 0; j < 2; j++)
          bf[j] = *(const half8*)&Bs[(wn + j * 16 + mrow) * LDB + h * 32 + q8];
        #pragma unroll
        for (int i = 0; i < 4; i++)
          #pragma unroll
          for (int j = 0; j < 2; j++)
            acc[i][j] = __builtin_amdgcn_mfma_f32_16x16x32_f16(af[i], bf[j], acc[i][j], 0, 0, 0);
      }
    }

    __syncthreads();
    u16* stage = Bs;
    #pragma unroll
    for (int j = 0; j < 2; j++) {
      float bv = bias[n0 + wn + j * 16 + ccol];
      #pragma unroll
      for (int i = 0; i < 4; i++) {
        #pragma unroll
        for (int r = 0; r < 4; r++) {
          int row = i * 16 + crow4 + r;
          stage[row * SSTR2 + wn + j * 16 + ccol] = f2h(acc[i][j][r] + bv);
        }
      }
    }
    __syncthreads();
    {
      int row = tid >> 2;
      int c0 = (tid & 3) * 32;
      int grow = bm + row;
      if (grow < M) {
        #pragma unroll
        for (int q = 0; q < 8; q++)
          *(ushort4*)&outp[(size_t)grow * H + n0 + c0 + q * 4] =
              *(const ushort4*)&stage[row * SSTR2 + c0 + q * 4];
      }
    }
  }
}

// gate GEMM: gate[row] += sum_col relu(x@Wg1 + bg1)[col] * Wg2[col]; gate pre-init to bg2
__global__ __launch_bounds__(256) void gemm_gate_kernel(
    const u16* __restrict__ A, const u16* __restrict__ W,
    const float* __restrict__ bias, const float* __restrict__ Wg2,
    float* __restrict__ gate, int M)
{
  __shared__ u16 smem[2 * GTM * LDB];
  u16* As = smem;
  u16* Bs = smem + GTM * LDB;
  int tid = threadIdx.x;
  int lane = tid & 63;
  int wave = tid >> 6;
  int wm = (wave >> 1) * 64;
  int wn = (wave & 1) * 64;
  int bm = blockIdx.y * GTM;
  int bn = blockIdx.x * 128;
  int lr = tid >> 3;
  int lc = (tid & 7) * 8;

  floatx4 zero4 = {0.f, 0.f, 0.f, 0.f};
  floatx4 acc[4][4];
  #pragma unroll
  for (int i = 0; i < 4; i++)
    #pragma unroll
    for (int j = 0; j < 4; j++) acc[i][j] = zero4;

  int q8 = (lane >> 4) * 8;
  int mrow = lane & 15;

  for (int k0 = 0; k0 < H; k0 += GTK) {
    __syncthreads();
    #pragma unroll
    for (int p = 0; p < 4; p++) {
      int row = lr + p * 32;
      int gr = bm + row;
      uint4 av = {0, 0, 0, 0};
      if (gr < M) av = *(const uint4*)&A[(size_t)gr * H + k0 + lc];
      *(uint4*)&As[row * LDB + lc] = av;
      uint4 bv = *(const uint4*)&W[(size_t)(bn + row) * H + k0 + lc];
      *(uint4*)&Bs[row * LDB + lc] = bv;
    }
    __syncthreads();
    #pragma unroll
    for (int h = 0; h < 2; h++) {
      half8 af[4], bf[4];
      #pragma unroll
      for (int i = 0; i < 4; i++)
        af[i] = *(const half8*)&As[(wm + i * 16 + mrow) * LDB + h * 32 + q8];
      #pragma unroll
      for (int j = 0; j < 4; j++)
        bf[j] = *(const half8*)&Bs[(wn + j * 16 + mrow) * LDB + h * 32 + q8];
      #pragma unroll
      for (int i = 0; i < 4; i++)
        #pragma unroll
        for (int j = 0; j < 4; j++)
          acc[i][j] = __builtin_amdgcn_mfma_f32_16x16x32_f16(af[i], bf[j], acc[i][j], 0, 0, 0);
    }
  }

  int ccol = lane & 15;
  float bv[4], wv[4];
  #pragma unroll
  for (int j = 0; j < 4; j++) {
    int col = bn + wn + j * 16 + ccol;
    bv[j] = bias[col];
    wv[j] = Wg2[col];
  }
  #pragma unroll
  for (int i = 0; i < 4; i++) {
    #pragma unroll
    for (int r = 0; r < 4; r++) {
      float p = 0.f;
      #pragma unroll
      for (int j = 0; j < 4; j++) {
        float hcol = fmaxf(acc[i][j][r] + bv[j], 0.f);
        p += hcol * wv[j];
      }
      p += __shfl_xor(p, 1, 64);
      p += __shfl_xor(p, 2, 64);
      p += __shfl_xor(p, 4, 64);
      p += __shfl_xor(p, 8, 64);
      int row = bm + wm + i * 16 + (lane >> 4) * 4 + r;
      if ((lane & 15) == 0 && row < M) atomicAdd(&gate[row], p);
    }
  }
}

// ---------------- edge scores: e[p] = dot(leaky(xl[src]+xr[dst]), att) ----------------
// 4 lanes per edge, 16 edges per wave; packed fp16; 2-shuffle quad reduce.
__global__ __launch_bounds__(256) void edge_score_kernel(
    const u16* __restrict__ xl, const u16* __restrict__ xr,
    const u16* __restrict__ att_h,
    const int* __restrict__ col, const int* __restrict__ rowdst,
    float* __restrict__ e_w)
{
  int tid = threadIdx.x;
  int lane = tid & 63;
  int wave = tid >> 6;
  int q = lane & 3;
  int ei = lane >> 2;
  int p = blockIdx.x * 64 + wave * 16 + ei;
  if (p >= EE) return;
  int u = col[p];
  int v = rowdst[p];
  const u16* xlrow = xl + (size_t)u * H + q * 64;
  const u16* xrrow = xr + (size_t)v * H + q * 64;
  const u16* at = att_h + q * 64;
  const half2v kslope = {(_Float16)NEG_SLOPE, (_Float16)NEG_SLOPE};
  float pe = 0.f;
  #pragma unroll
  for (int i = 0; i < 8; i++) {
    uint4 aq = *(const uint4*)&xlrow[i * 8];
    uint4 bq = *(const uint4*)&xrrow[i * 8];
    uint4 tq = *(const uint4*)&at[i * 8];
    unsigned int ap[4] = {aq.x, aq.y, aq.z, aq.w};
    unsigned int bp[4] = {bq.x, bq.y, bq.z, bq.w};
    unsigned int tp[4] = {tq.x, tq.y, tq.z, tq.w};
    #pragma unroll
    for (int c = 0; c < 4; c++) {
      half2v a = __builtin_bit_cast(half2v, ap[c]);
      half2v b = __builtin_bit_cast(half2v, bp[c]);
      half2v t = __builtin_bit_cast(half2v, tp[c]);
      half2v h = a + b;
      half2v l = __builtin_elementwise_max(h, h * kslope);
#if __has_builtin(__builtin_amdgcn_fdot2)
      pe = __builtin_amdgcn_fdot2(l, t, pe, false);
#else
      pe += (float)l[0] * (float)t[0] + (float)l[1] * (float)t[1];
#endif
    }
  }
  pe += __shfl_xor(pe, 1, 64);
  pe += __shfl_xor(pe, 2, 64);
  if (q == 0) e_w[p] = pe;
}

// ---------------- aggregate: segment softmax + weighted sum + LN + residual ----------------
// One wave per node; softmax stats from precomputed e_w (2 wave-reduces total);
// aggregation loop has no shuffle-reduce chain.
__global__ __launch_bounds__(256) void layer_agg_kernel(
    const u16* __restrict__ xl, u16* __restrict__ xst,
    const int* __restrict__ rowp, const int* __restrict__ col,
    const float* __restrict__ e_w,
    const float* __restrict__ bias_c,
    const float* __restrict__ ln_g, const float* __restrict__ ln_b)
{
  int lane = threadIdx.x & 63;
  int v = blockIdx.x * 4 + (threadIdx.x >> 6);
  if (v >= N_NODES) return;
  int f4 = lane << 2;
  size_t rowbase = (size_t)v * H;
  int beg = rowp[v], end = rowp[v + 1];
  int deg = end - beg;

  // softmax stats
  float lm = -INFINITY;
  for (int j = lane; j < deg; j += 64) lm = fmaxf(lm, e_w[beg + j]);
  #pragma unroll
  for (int off = 32; off > 0; off >>= 1) lm = fmaxf(lm, __shfl_xor(lm, off, 64));
  float m = lm;
  float wreg = 0.f;
  int colreg = 0;
  float lsum = 0.f;
  for (int j = lane; j < deg; j += 64) {
    float wj = __expf(e_w[beg + j] - m);
    if (j < 64) { wreg = wj; colreg = col[beg + j]; }
    lsum += wj;
  }
  float d = wave_reduce_sum(lsum);
  float invd = 1.0f / d;

  // weighted aggregation (no serial reduce chains)
  float o0 = 0.f, o1 = 0.f, o2 = 0.f, o3 = 0.f;
  int jmax = min(deg, 64);
  for (int j = 0; j < jmax; j++) {
    float wgt = __shfl(wreg, j, 64);
    int u = __shfl(colreg, j, 64);
    uint2 aq = *(const uint2*)&xl[(size_t)u * H + f4];
    half2v a0 = __builtin_bit_cast(half2v, aq.x);
    half2v a1 = __builtin_bit_cast(half2v, aq.y);
    o0 = fmaf(wgt, (float)a0[0], o0);
    o1 = fmaf(wgt, (float)a0[1], o1);
    o2 = fmaf(wgt, (float)a1[0], o2);
    o3 = fmaf(wgt, (float)a1[1], o3);
  }
  for (int j = 64; j < deg; j++) {  // rare: degree > 64
    float wgt = __expf(e_w[beg + j] - m);
    int u = col[beg + j];
    uint2 aq = *(const uint2*)&xl[(size_t)u * H + f4];
    half2v a0 = __builtin_bit_cast(half2v, aq.x);
    half2v a1 = __builtin_bit_cast(half2v, aq.y);
    o0 = fmaf(wgt, (float)a0[0], o0);
    o1 = fmaf(wgt, (float)a0[1], o1);
    o2 = fmaf(wgt, (float)a1[0], o2);
    o3 = fmaf(wgt, (float)a1[1], o3);
  }

  float4 bc4 = *(const float4*)&bias_c[f4];
  float ox = fmaf(o0, invd, bc4.x);
  float oy = fmaf(o1, invd, bc4.y);
  float oz = fmaf(o2, invd, bc4.z);
  float ow = fmaf(o3, invd, bc4.w);
  float s = wave_reduce_sum(ox + oy + oz + ow);
  float mean = s * (1.0f / H);
  float cx = ox - mean, cy = oy - mean, cz = oz - mean, cw = ow - mean;
  float sq = wave_reduce_sum(cx * cx + cy * cy + cz * cz + cw * cw);
  float rstd = rsqrtf(sq * (1.0f / H) + LN_EPS);
  float4 g4 = *(const float4*)&ln_g[f4];
  float4 b4 = *(const float4*)&ln_b[f4];
  uint2 resq = *(const uint2*)&xst[rowbase + f4];
  half2v r0 = __builtin_bit_cast(half2v, resq.x);
  half2v r1 = __builtin_bit_cast(half2v, resq.y);
  float yx = fmaxf(fmaf(cx * rstd, g4.x, b4.x), 0.f) + (float)r0[0];
  float yy = fmaxf(fmaf(cy * rstd, g4.y, b4.y), 0.f) + (float)r0[1];
  float yz = fmaxf(fmaf(cz * rstd, g4.z, b4.z), 0.f) + (float)r1[0];
  float yw = fmaxf(fmaf(cw * rstd, g4.w, b4.w), 0.f) + (float)r1[1];
  ushort4 yb;
  yb.x = f2h(yx); yb.y = f2h(yy); yb.z = f2h(yz); yb.w = f2h(yw);
  *(ushort4*)&xst[rowbase + f4] = yb;
}

// ---------------- gate init (+ graph-bounds defaults) ----------------
__global__ void gate_init_kernel(float* __restrict__ gate, const float* __restrict__ bg2,
                                 int* __restrict__ gstart, int* __restrict__ gend) {
  int i = blockIdx.x * 256 + threadIdx.x;
  if (i < N_NODES) gate[i] = bg2[0];
  if (i < NGRAPH) { gstart[i] = 0; gend[i] = 0; }
}

// ---------------- graph bounds (sorted batch) ----------------
__global__ void gbounds_kernel(const int* __restrict__ batch, int* __restrict__ gstart,
                               int* __restrict__ gend) {
  int i = blockIdx.x * 256 + threadIdx.x;
  if (i < N_NODES) {
    int b = batch[i];
    if (i == 0 || batch[i - 1] != b) gstart[b] = i;
    if (i == N_NODES - 1 || batch[i + 1] != b) gend[b] = i + 1;
  }
}

// ---------------- pooling: per-graph softmax stats (+ pooled zero) ----------------
__global__ __launch_bounds__(256) void pool_prep_kernel(
    const float* __restrict__ gate, const int* __restrict__ gstart,
    const int* __restrict__ gend, float* __restrict__ gmax, float* __restrict__ gdinv,
    float* __restrict__ pooled)
{
  __shared__ float red[256];
  int g = blockIdx.x, tid = threadIdx.x;
  pooled[(size_t)g * H + tid] = 0.f;
  int s = gstart[g], e = gend[g];
  float lm = -INFINITY;
  for (int i = s + tid; i < e; i += 256) lm = fmaxf(lm, gate[i]);
  red[tid] = lm;
  __syncthreads();
  for (int off = 128; off; off >>= 1) {
    if (tid < off) red[tid] = fmaxf(red[tid], red[tid + off]);
    __syncthreads();
  }
  float m = red[0];
  __syncthreads();
  float lsum = 0.0f;
  for (int i = s + tid; i < e; i += 256) lsum += __expf(gate[i] - m);
  red[tid] = lsum;
  __syncthreads();
  for (int off = 128; off; off >>= 1) {
    if (tid < off) red[tid] += red[tid + off];
    __syncthreads();
  }
  if (tid == 0) {
    gmax[g] = m;
    gdinv[g] = (s < e) ? 1.0f / red[0] : 0.0f;
  }
}

// ---------------- pooling: weighted accumulate (128 nodes per block, fp16 x) ----------------
__global__ __launch_bounds__(256) void pool_accum_kernel(
    const float* __restrict__ gate, const u16* __restrict__ xh,
    const int* __restrict__ batch, const float* __restrict__ gmax,
    const float* __restrict__ gdinv, float* __restrict__ pooled)
{
  __shared__ float wl[128];
  __shared__ int gl[128];
  int b0 = blockIdx.x * 128;
  int tid = threadIdx.x;
  if (tid < 128) {
    int v = b0 + tid;
    if (v < N_NODES) {
      int g = batch[v];
      gl[tid] = g;
      wl[tid] = __expf(gate[v] - gmax[g]) * gdinv[g];
    } else {
      gl[tid] = -1;
      wl[tid] = 0.f;
    }
  }
  __syncthreads();
  int cnt = min(128, N_NODES - b0);
  float acc = 0.f;
  int cur = gl[0];
  for (int j = 0; j < cnt; j++) {
    int g = gl[j];
    if (g != cur) {
      atomicAdd(&pooled[(size_t)cur * H + tid], acc);
      acc = 0.f;
      cur = g;
    }
    acc += wl[j] * h2f(xh[(size_t)(b0 + j) * H + tid]);
  }
  if (cur >= 0) atomicAdd(&pooled[(size_t)cur * H + tid], acc);
}

// ---------------- fused head: pooled -> z -> {cls, r1} -> residual ----------------
__global__ __launch_bounds__(256) void head_kernel(
    const float* __restrict__ pooled,
    const float* __restrict__ Ws, const float* __restrict__ bs,
    const float* __restrict__ Wc, const float* __restrict__ bc,
    const float* __restrict__ Wr1, const float* __restrict__ br1,
    const float* __restrict__ Wr2, const float* __restrict__ br2,
    float* __restrict__ out)
{
  __shared__ float psh[256];
  __shared__ float zsh[256];
  __shared__ float r1sh[128];
  int g = blockIdx.x, tid = threadIdx.x;
  psh[tid] = pooled[(size_t)g * H + tid];
  __syncthreads();
  {
    float acc = bs[tid];
    const float4* wr = (const float4*)&Ws[(size_t)tid * H];
    for (int k4 = 0; k4 < H / 4; k4++) {
      float4 wv = wr[k4];
      float4 av = *(const float4*)&psh[k4 * 4];
      acc += av.x * wv.x + av.y * wv.y + av.z * wv.z + av.w * wv.w;
    }
    zsh[tid] = fmaxf(acc, 0.f);
  }
  __syncthreads();
  if (tid < NB) {
    float acc = bc[tid];
    const float4* wr = (const float4*)&Wc[(size_t)tid * H];
    for (int k4 = 0; k4 < H / 4; k4++) {
      float4 wv = wr[k4];
      float4 av = *(const float4*)&zsh[k4 * 4];
      acc += av.x * wv.x + av.y * wv.y + av.z * wv.z + av.w * wv.w;
    }
    out[(size_t)g * NB + tid] = acc;
  }
  if (tid < 128) {
    float acc = br1[tid];
    const float4* wr = (const float4*)&Wr1[(size_t)tid * H];
    for (int k4 = 0; k4 < H / 4; k4++) {
      float4 wv = wr[k4];
      float4 av = *(const float4*)&zsh[k4 * 4];
      acc += av.x * wv.x + av.y * wv.y + av.z * wv.z + av.w * wv.w;
    }
    r1sh[tid] = fmaxf(acc, 0.f);
  }
  __syncthreads();
  if (tid < 64) {
    float s2 = r1sh[tid] * Wr2[tid] + r1sh[tid + 64] * Wr2[tid + 64];
    s2 = wave_reduce_sum(s2);
    if (tid == 0) out[(size_t)NGRAPH * NB + g] = tanhf(s2 + br2[0]);
  }
}

// ---------------- launcher ----------------
extern "C" void kernel_launch(void* const* d_in, const int* in_sizes, int n_in,
                              void* d_out, int out_size, void* d_ws, size_t ws_size,
                              hipStream_t stream) {
  const float* x_in   = (const float*)d_in[0];
  const int*   eidx   = (const int*)d_in[1];
  const int*   batch  = (const int*)d_in[2];
  const float* W_in   = (const float*)d_in[3];
  const float* b_in   = (const float*)d_in[4];
  const float* Wl     = (const float*)d_in[5];
  const float* bl     = (const float*)d_in[6];
  const float* Wr     = (const float*)d_in[7];
  const float* br     = (const float*)d_in[8];
  const float* att    = (const float*)d_in[9];
  const float* bias_c = (const float*)d_in[10];
  const float* ln_g   = (const float*)d_in[11];
  const float* ln_b   = (const float*)d_in[12];
  const float* Wg1    = (const float*)d_in[13];
  const float* bg1    = (const float*)d_in[14];
  const float* Wg2    = (const float*)d_in[15];
  const float* bg2    = (const float*)d_in[16];
  const float* Ws     = (const float*)d_in[17];
  const float* bs     = (const float*)d_in[18];
  const float* Wc     = (const float*)d_in[19];
  const float* bc     = (const float*)d_in[20];
  const float* Wr1    = (const float*)d_in[21];
  const float* br1    = (const float*)d_in[22];
  const float* Wr2    = (const float*)d_in[23];
  const float* br2    = (const float*)d_in[24];
  float* out = (float*)d_out;

  char* w = (char*)d_ws;
  u16* x_h    = (u16*)w;    w += sizeof(u16) * (size_t)N_NODES * H;
  u16* xl_h   = (u16*)w;    w += sizeof(u16) * (size_t)N_NODES * H;
  u16* xr_h   = (u16*)w;    w += sizeof(u16) * (size_t)N_NODES * H;
  u16* xin_h  = (u16*)w;    w += sizeof(u16) * (size_t)N_NODES * IN_DIM;
  u16* win_h  = (u16*)w;    w += sizeof(u16) * (size_t)H * IN_DIM;
  u16* wl_h   = (u16*)w;    w += sizeof(u16) * (size_t)LAYERS * H * H;
  u16* wr_h   = (u16*)w;    w += sizeof(u16) * (size_t)LAYERS * H * H;
  u16* wg1_h  = (u16*)w;    w += sizeof(u16) * (size_t)H * H;
  u16* att_h  = (u16*)w;    w += sizeof(u16) * (size_t)LAYERS * H;
  float* e_w  = (float*)w;  w += sizeof(float) * EE;
  float* pooled = (float*)w; w += sizeof(float) * NGRAPH * H;
  float* gate = (float*)w;  w += sizeof(float) * N_NODES;
  float* gmax = (float*)w;  w += sizeof(float) * NGRAPH;
  float* gdinv= (float*)w;  w += sizeof(float) * NGRAPH;
  int* cnt    = (int*)w;    w += sizeof(int) * N_NODES;
  int* rowp   = (int*)w;    w += sizeof(int) * (N_NODES + 1);
  int* col    = (int*)w;    w += sizeof(int) * EE;
  int* rowdst = (int*)w;    w += sizeof(int) * EE;
  int* partial= (int*)w;    w += sizeof(int) * N_NODES;
  int* bsums  = (int*)w;    w += sizeof(int) * 256;
  int* gstart = (int*)w;    w += sizeof(int) * NGRAPH;
  int* gend   = (int*)w;    w += sizeof(int) * NGRAPH;
  (void)ws_size; (void)n_in; (void)in_sizes; (void)out_size;

  const int* src = eidx;
  const int* dst = eidx + N_EDGES;
  int nblkN = (N_NODES + 255) / 256;
  int nblkE = (N_EDGES + 255) / 256;
  int mtiles = (N_NODES + GTM - 1) / GTM;
  int mtiles2 = (N_NODES + DTM - 1) / DTM;
  int sblk = (EE + 63) / 64;

  // CSR build (by dst, self-loops included)
  init_counts_kernel<<<nblkN, 256, 0, stream>>>(cnt);
  count_edges_kernel<<<nblkE, 256, 0, stream>>>(dst, cnt);
  scan_blocks_kernel<<<nblkN, 256, 0, stream>>>(cnt, partial, bsums, N_NODES);
  scan_sums_kernel<<<1, 256, 0, stream>>>(bsums, nblkN);
  scan_write_kernel<<<nblkN, 256, 0, stream>>>(partial, bsums, rowp, N_NODES);
  fill_self_kernel<<<nblkN, 256, 0, stream>>>(rowp, col, rowdst, cnt);
  fill_edges_kernel<<<nblkE, 256, 0, stream>>>(src, dst, cnt, col, rowdst);

  // casts
  {
    int maxn4 = LAYERS * H * H / 4;
    dim3 gcast((maxn4 + 255) / 256, 5);
    cast_weights_kernel<<<gcast, 256, 0, stream>>>(W_in, Wg1, Wl, Wr, att,
                                                   win_h, wg1_h, wl_h, wr_h, att_h);
    int n4 = N_NODES * IN_DIM / 4;
    cast_f16_kernel<<<(n4 + 255) / 256, 256, 0, stream>>>(x_in, xin_h, n4);
  }

  // input projection -> x_h
  dim3 gproj(2, mtiles);
  gemm_proj_kernel<<<gproj, 256, 0, stream>>>(xin_h, win_h, b_in, x_h, N_NODES, IN_DIM);

  int nblkV = N_NODES / 4;
  for (int l = 0; l < LAYERS; l++) {
    gemm_dual2_kernel<<<mtiles2, 256, 0, stream>>>(x_h,
        wl_h + (size_t)l * H * H, wr_h + (size_t)l * H * H,
        bl + l * H, br + l * H, xl_h, xr_h, N_NODES);
    edge_score_kernel<<<sblk, 256, 0, stream>>>(xl_h, xr_h, att_h + l * H,
        col, rowdst, e_w);
    layer_agg_kernel<<<nblkV, 256, 0, stream>>>(xl_h, x_h, rowp, col, e_w,
        bias_c + l * H, ln_g + l * H, ln_b + l * H);
  }

  // gate (fused GEMM + row-dot)
  gate_init_kernel<<<nblkN, 256, 0, stream>>>(gate, bg2, gstart, gend);
  dim3 ggate(2, mtiles);
  gemm_gate_kernel<<<ggate, 256, 0, stream>>>(x_h, wg1_h, bg1, Wg2, gate, N_NODES);

  // pooling
  gbounds_kernel<<<nblkN, 256, 0, stream>>>(batch, gstart, gend);
  pool_prep_kernel<<<NGRAPH, 256, 0, stream>>>(gate, gstart, gend, gmax, gdinv, pooled);
  pool_accum_kernel<<<(N_NODES + 127) / 128, 256, 0, stream>>>(gate, x_h, batch, gmax, gdinv, pooled);

  // fused heads
  head_kernel<<<NGRAPH, 256, 0, stream>>>(pooled, Ws, bs, Wc, bc, Wr1, br1, Wr2, br2, out);
}

// Round 11
// 631.335 us; speedup vs baseline: 1.3629x; 1.3629x over previous
//
#include <hip/hip_runtime.h>
#include <math.h>

#define N_NODES 50000
#define N_EDGES 300000
#define IN_DIM 64
#define H 256
#define LAYERS 4
#define NB 181
#define NGRAPH 64
#define EE (N_EDGES + N_NODES)
#define NEG_SLOPE 0.2f
#define LN_EPS 1e-5f

typedef unsigned short u16;
typedef __attribute__((ext_vector_type(8))) _Float16 half8;
typedef __attribute__((ext_vector_type(2))) _Float16 half2v;
typedef __attribute__((ext_vector_type(4))) float floatx4;

__device__ __forceinline__ u16 f2h(float f) {
  _Float16 h = (_Float16)f;
  return __builtin_bit_cast(u16, h);
}
__device__ __forceinline__ float h2f(u16 b) {
  return (float)__builtin_bit_cast(_Float16, b);
}

__device__ __forceinline__ float wave_reduce_sum(float v) {
  #pragma unroll
  for (int off = 32; off > 0; off >>= 1) v += __shfl_xor(v, off, 64);
  return v;
}

// ---------------- casts ----------------
__global__ void cast_f16_kernel(const float* __restrict__ in, u16* __restrict__ out, int n4) {
  int i = blockIdx.x * 256 + threadIdx.x;
  if (i < n4) {
    float4 f = ((const float4*)in)[i];
    ushort4 o;
    o.x = f2h(f.x); o.y = f2h(f.y); o.z = f2h(f.z); o.w = f2h(f.w);
    ((ushort4*)out)[i] = o;
  }
}

__global__ void cast_weights_kernel(
    const float* __restrict__ W_in, const float* __restrict__ Wg1,
    const float* __restrict__ Wl, const float* __restrict__ Wr,
    u16* __restrict__ win_h, u16* __restrict__ wg1_h,
    u16* __restrict__ wl_h, u16* __restrict__ wr_h)
{
  int i = blockIdx.x * 256 + threadIdx.x;
  int which = blockIdx.y;
  const float* s; u16* dd; int n4;
  if (which == 0)      { s = W_in; dd = win_h; n4 = H * IN_DIM / 4; }
  else if (which == 1) { s = Wg1;  dd = wg1_h; n4 = H * H / 4; }
  else if (which == 2) { s = Wl;   dd = wl_h;  n4 = LAYERS * H * H / 4; }
  else                 { s = Wr;   dd = wr_h;  n4 = LAYERS * H * H / 4; }
  if (i < n4) {
    float4 f = ((const float4*)s)[i];
    ushort4 o;
    o.x = f2h(f.x); o.y = f2h(f.y); o.z = f2h(f.z); o.w = f2h(f.w);
    ((ushort4*)dd)[i] = o;
  }
}

// ---------------- CSR build ----------------
__global__ void init_counts_kernel(int* __restrict__ cnt) {
  int i = blockIdx.x * 256 + threadIdx.x;
  if (i < N_NODES) cnt[i] = 1;  // self loop
}

__global__ void count_edges_kernel(const int* __restrict__ dst, int* __restrict__ cnt) {
  int e = blockIdx.x * 256 + threadIdx.x;
  if (e < N_EDGES) atomicAdd(&cnt[dst[e]], 1);
}

__global__ void scan_blocks_kernel(const int* __restrict__ cnt, int* __restrict__ partial,
                                   int* __restrict__ bsums, int n) {
  __shared__ int buf[256];
  int tid = threadIdx.x;
  int i = blockIdx.x * 256 + tid;
  buf[tid] = (i < n) ? cnt[i] : 0;
  __syncthreads();
  #pragma unroll
  for (int off = 1; off < 256; off <<= 1) {
    int t = (tid >= off) ? buf[tid - off] : 0;
    __syncthreads();
    buf[tid] += t;
    __syncthreads();
  }
  if (i < n) partial[i] = buf[tid];
  if (tid == 255) bsums[blockIdx.x] = buf[255];
}

__global__ void scan_sums_kernel(int* __restrict__ bsums, int nblk) {
  __shared__ int buf[256];
  int tid = threadIdx.x;
  buf[tid] = (tid < nblk) ? bsums[tid] : 0;
  __syncthreads();
  #pragma unroll
  for (int off = 1; off < 256; off <<= 1) {
    int t = (tid >= off) ? buf[tid - off] : 0;
    __syncthreads();
    buf[tid] += t;
    __syncthreads();
  }
  if (tid < nblk) bsums[tid] = buf[tid];
}

__global__ void scan_write_kernel(const int* __restrict__ partial, const int* __restrict__ bsums,
                                  int* __restrict__ rowp, int n) {
  int i = blockIdx.x * 256 + threadIdx.x;
  if (i < n) {
    int b = blockIdx.x;
    int off = (b > 0) ? bsums[b - 1] : 0;
    rowp[i + 1] = partial[i] + off;
    if (i == 0) rowp[0] = 0;
  }
}

__global__ void fill_self_kernel(const int* __restrict__ rowp, int* __restrict__ col,
                                 int* __restrict__ fillpos) {
  int i = blockIdx.x * 256 + threadIdx.x;
  if (i < N_NODES) {
    int p = rowp[i];
    col[p] = i;
    fillpos[i] = p + 1;
  }
}

__global__ void fill_edges_kernel(const int* __restrict__ src, const int* __restrict__ dst,
                                  int* __restrict__ fillpos, int* __restrict__ col) {
  int e = blockIdx.x * 256 + threadIdx.x;
  if (e < N_EDGES) {
    int d = dst[e];
    int p = atomicAdd(&fillpos[d], 1);
    col[p] = src[e];
  }
}

// ---------------- MFMA GEMM tiles ----------------
#define GTM 128
#define GTK 64
#define LDB 72
#define SSTR 132

__global__ __launch_bounds__(256) void gemm_proj_kernel(
    const u16* __restrict__ A, const u16* __restrict__ W,
    const float* __restrict__ bias, u16* __restrict__ outh, int M, int K)
{
  __shared__ u16 smem[2 * GTM * LDB];
  u16* As = smem;
  u16* Bs = smem + GTM * LDB;
  int tid = threadIdx.x;
  int lane = tid & 63;
  int wave = tid >> 6;
  int wm = (wave >> 1) * 64;
  int wn = (wave & 1) * 64;
  int bm = blockIdx.y * GTM;
  int n0 = blockIdx.x * 128;
  int lr = tid >> 3;
  int lc = (tid & 7) * 8;

  floatx4 zero4 = {0.f, 0.f, 0.f, 0.f};
  floatx4 acc[4][4];
  #pragma unroll
  for (int i = 0; i < 4; i++)
    #pragma unroll
    for (int j = 0; j < 4; j++) acc[i][j] = zero4;

  int q8 = (lane >> 4) * 8;
  int mrow = lane & 15;

  for (int k0 = 0; k0 < K; k0 += GTK) {
    __syncthreads();
    #pragma unroll
    for (int p = 0; p < 4; p++) {
      int row = lr + p * 32;
      int gr = bm + row;
      uint4 av = {0, 0, 0, 0};
      if (gr < M) av = *(const uint4*)&A[(size_t)gr * K + k0 + lc];
      *(uint4*)&As[row * LDB + lc] = av;
      uint4 bv = *(const uint4*)&W[(size_t)(n0 + row) * K + k0 + lc];
      *(uint4*)&Bs[row * LDB + lc] = bv;
    }
    __syncthreads();
    #pragma unroll
    for (int h = 0; h < 2; h++) {
      half8 af[4], bf[4];
      #pragma unroll
      for (int i = 0; i < 4; i++)
        af[i] = *(const half8*)&As[(wm + i * 16 + mrow) * LDB + h * 32 + q8];
      #pragma unroll
      for (int j = 0; j < 4; j++)
        bf[j] = *(const half8*)&Bs[(wn + j * 16 + mrow) * LDB + h * 32 + q8];
      #pragma unroll
      for (int i = 0; i < 4; i++)
        #pragma unroll
        for (int j = 0; j < 4; j++)
          acc[i][j] = __builtin_amdgcn_mfma_f32_16x16x32_f16(af[i], bf[j], acc[i][j], 0, 0, 0);
    }
  }

  __syncthreads();
  u16* stage = smem;
  int ccol = lane & 15;
  int crow4 = (lane >> 4) * 4;
  #pragma unroll
  for (int j = 0; j < 4; j++) {
    float bv = bias[n0 + wn + j * 16 + ccol];
    #pragma unroll
    for (int i = 0; i < 4; i++) {
      #pragma unroll
      for (int r = 0; r < 4; r++) {
        int row = wm + i * 16 + crow4 + r;
        stage[row * SSTR + wn + j * 16 + ccol] = f2h(acc[i][j][r] + bv);
      }
    }
  }
  __syncthreads();
  int rr = tid >> 1;
  int c0 = (tid & 1) * 64;
  int grow = bm + rr;
  if (grow < M) {
    const ushort4* sp = (const ushort4*)&stage[rr * SSTR + c0];
    ushort4* gp = (ushort4*)&outh[(size_t)grow * H + n0 + c0];
    #pragma unroll
    for (int q = 0; q < 16; q++) gp[q] = sp[q];
  }
}

// ---------------- dual GEMM v2: A-resident in LDS, 64-row m-tiles ----------------
#define DTM 64
#define AST 264
#define SSTR2 132

__global__ __launch_bounds__(256) void gemm_dual2_kernel(
    const u16* __restrict__ A, const u16* __restrict__ Wlb, const u16* __restrict__ Wrb,
    const float* __restrict__ biasL, const float* __restrict__ biasR,
    u16* __restrict__ outL, u16* __restrict__ outR, int M)
{
  __shared__ u16 As[DTM * AST];
  __shared__ u16 Bs[128 * LDB];
  int tid = threadIdx.x;
  int lane = tid & 63;
  int wave = tid >> 6;
  int wn = wave * 32;
  int bm = blockIdx.x * DTM;
  int mrow = lane & 15;
  int q8 = (lane >> 4) * 8;
  int ccol = lane & 15;
  int crow4 = (lane >> 4) * 4;

  {
    int col = (tid & 31) * 8;
    int r0 = tid >> 5;
    #pragma unroll
    for (int it = 0; it < 8; it++) {
      int row = r0 + it * 8;
      int gr = bm + row;
      uint4 av = {0, 0, 0, 0};
      if (gr < M) av = *(const uint4*)&A[(size_t)gr * H + col];
      *(uint4*)&As[row * AST + col] = av;
    }
  }

  floatx4 zero4 = {0.f, 0.f, 0.f, 0.f};

  for (int nt = 0; nt < 4; nt++) {
    const u16* W = (nt < 2) ? Wlb : Wrb;
    const float* bias = (nt < 2) ? biasL : biasR;
    u16* outp = (nt < 2) ? outL : outR;
    int n0 = (nt & 1) * 128;

    floatx4 acc[4][2];
    #pragma unroll
    for (int i = 0; i < 4; i++) {
      acc[i][0] = zero4;
      acc[i][1] = zero4;
    }

    for (int k0 = 0; k0 < H; k0 += 64) {
      __syncthreads();
      {
        int col = (tid & 7) * 8;
        int r0 = tid >> 3;
        #pragma unroll
        for (int p2 = 0; p2 < 4; p2++) {
          int row = r0 + p2 * 32;
          uint4 bv = *(const uint4*)&W[(size_t)(n0 + row) * H + k0 + col];
          *(uint4*)&Bs[row * LDB + col] = bv;
        }
      }
      __syncthreads();
      #pragma unroll
      for (int h = 0; h < 2; h++) {
        half8 af[4], bf[2];
        #pragma unroll
        for (int i = 0; i < 4; i++)
          af[i] = *(const half8*)&As[(i * 16 + mrow) * AST + k0 + h * 32 + q8];
        #pragma unroll
        for (int j = 0; j < 2; j++)
          bf[j] = *(const half8*)&Bs[(wn + j * 16 + mrow) * LDB + h * 32 + q8];
        #pragma unroll
        for (int i = 0; i < 4; i++)
          #pragma unroll
          for (int j = 0; j < 2; j++)
            acc[i][j] = __builtin_amdgcn_mfma_f32_16x16x32_f16(af[i], bf[j], acc[i][j], 0, 0, 0);
      }
    }

    __syncthreads();
    u16* stage = Bs;
    #pragma unroll
    for (int j = 0; j < 2; j++) {
      float bv = bias[n0 + wn + j * 16 + ccol];
      #pragma unroll
      for (int i = 0; i < 4; i++) {
        #pragma unroll
        for (int r = 0; r < 4; r++) {
          int row = i * 16 + crow4 + r;
          stage[row * SSTR2 + wn + j * 16 + ccol] = f2h(acc[i][j][r] + bv);
        }
      }
    }
    __syncthreads();
    {
      int row = tid >> 2;
      int c0 = (tid & 3) * 32;
      int grow = bm + row;
      if (grow < M) {
        #pragma unroll
        for (int q = 0; q < 8; q++)
          *(ushort4*)&outp[(size_t)grow * H + n0 + c0 + q * 4] =
              *(const ushort4*)&stage[row * SSTR2 + c0 + q * 4];
      }
    }
  }
}

// gate GEMM: gate[row] += sum_col relu(x@Wg1 + bg1)[col] * Wg2[col]; gate pre-init to bg2
__global__ __launch_bounds__(256) void gemm_gate_kernel(
    const u16* __restrict__ A, const u16* __restrict__ W,
    const float* __restrict__ bias, const float* __restrict__ Wg2,
    float* __restrict__ gate, int M)
{
  __shared__ u16 smem[2 * GTM * LDB];
  u16* As = smem;
  u16* Bs = smem + GTM * LDB;
  int tid = threadIdx.x;
  int lane = tid & 63;
  int wave = tid >> 6;
  int wm = (wave >> 1) * 64;
  int wn = (wave & 1) * 64;
  int bm = blockIdx.y * GTM;
  int bn = blockIdx.x * 128;
  int lr = tid >> 3;
  int lc = (tid & 7) * 8;

  floatx4 zero4 = {0.f, 0.f, 0.f, 0.f};
  floatx4 acc[4][4];
  #pragma unroll
  for (int i = 0; i < 4; i++)
    #pragma unroll
    for (int j = 0; j < 4; j++) acc[i][j] = zero4;

  int q8 = (lane >> 4) * 8;
  int mrow = lane & 15;

  for (int k0 = 0; k0 < H; k0 += GTK) {
    __syncthreads();
    #pragma unroll
    for (int p = 0; p < 4; p++) {
      int row = lr + p * 32;
      int gr = bm + row;
      uint4 av = {0, 0, 0, 0};
      if (gr < M) av = *(const uint4*)&A[(size_t)gr * H + k0 + lc];
      *(uint4*)&As[row * LDB + lc] = av;
      uint4 bv = *(const uint4*)&W[(size_t)(bn + row) * H + k0 + lc];
      *(uint4*)&Bs[row * LDB + lc] = bv;
    }
    __syncthreads();
    #pragma unroll
    for (int h = 0; h < 2; h++) {
      half8 af[4], bf[4];
      #pragma unroll
      for (int i = 0; i < 4; i++)
        af[i] = *(const half8*)&As[(wm + i * 16 + mrow) * LDB + h * 32 + q8];
      #pragma unroll
      for (int j = 0; j < 4; j++)
        bf[j] = *(const half8*)&Bs[(wn + j * 16 + mrow) * LDB + h * 32 + q8];
      #pragma unroll
      for (int i = 0; i < 4; i++)
        #pragma unroll
        for (int j = 0; j < 4; j++)
          acc[i][j] = __builtin_amdgcn_mfma_f32_16x16x32_f16(af[i], bf[j], acc[i][j], 0, 0, 0);
    }
  }

  int ccol = lane & 15;
  float bv[4], wv[4];
  #pragma unroll
  for (int j = 0; j < 4; j++) {
    int col = bn + wn + j * 16 + ccol;
    bv[j] = bias[col];
    wv[j] = Wg2[col];
  }
  #pragma unroll
  for (int i = 0; i < 4; i++) {
    #pragma unroll
    for (int r = 0; r < 4; r++) {
      float p = 0.f;
      #pragma unroll
      for (int j = 0; j < 4; j++) {
        float hcol = fmaxf(acc[i][j][r] + bv[j], 0.f);
        p += hcol * wv[j];
      }
      p += __shfl_xor(p, 1, 64);
      p += __shfl_xor(p, 2, 64);
      p += __shfl_xor(p, 4, 64);
      p += __shfl_xor(p, 8, 64);
      int row = bm + wm + i * 16 + (lane >> 4) * 4 + r;
      if ((lane & 15) == 0 && row < M) atomicAdd(&gate[row], p);
    }
  }
}

// ---------------- fused edge softmax + aggregate + LN + residual ----------------
// R6 structure: 1 node/wave, 64 lanes x 4 feats, unroll-2 dual interleaved chains,
// fp16 storage, expanded fp32 math (measured-best at 54 us/layer).
__global__ __launch_bounds__(256) void layer_fused_kernel(
    const u16* __restrict__ xl, const u16* __restrict__ xr,
    u16* __restrict__ xst,
    const int* __restrict__ rowp, const int* __restrict__ col,
    const float* __restrict__ att, const float* __restrict__ bias_c,
    const float* __restrict__ ln_g, const float* __restrict__ ln_b)
{
  int lane = threadIdx.x & 63;
  int v = blockIdx.x * 4 + (threadIdx.x >> 6);
  if (v >= N_NODES) return;
  int f4 = lane << 2;
  size_t rowbase = (size_t)v * H;
  ushort4 xr4 = *(const ushort4*)&xr[rowbase + f4];
  float xrx = h2f(xr4.x), xry = h2f(xr4.y), xrz = h2f(xr4.z), xrw = h2f(xr4.w);
  float4 attv = *(const float4*)&att[f4];
  int beg = rowp[v], end = rowp[v + 1];
  float m = -INFINITY, d = 0.f;
  float ox = 0.f, oy = 0.f, oz = 0.f, ow = 0.f;
  int p = beg;
  for (; p + 2 <= end; p += 2) {
    int u0 = col[p];
    int u1 = col[p + 1];
    ushort4 a04 = *(const ushort4*)&xl[(size_t)u0 * H + f4];
    ushort4 a14 = *(const ushort4*)&xl[(size_t)u1 * H + f4];
    float a0x = h2f(a04.x), a0y = h2f(a04.y), a0z = h2f(a04.z), a0w = h2f(a04.w);
    float a1x = h2f(a14.x), a1y = h2f(a14.y), a1z = h2f(a14.z), a1w = h2f(a14.w);
    float t0x = a0x + xrx; t0x = t0x > 0.f ? t0x : NEG_SLOPE * t0x;
    float t0y = a0y + xry; t0y = t0y > 0.f ? t0y : NEG_SLOPE * t0y;
    float t0z = a0z + xrz; t0z = t0z > 0.f ? t0z : NEG_SLOPE * t0z;
    float t0w = a0w + xrw; t0w = t0w > 0.f ? t0w : NEG_SLOPE * t0w;
    float t1x = a1x + xrx; t1x = t1x > 0.f ? t1x : NEG_SLOPE * t1x;
    float t1y = a1y + xry; t1y = t1y > 0.f ? t1y : NEG_SLOPE * t1y;
    float t1z = a1z + xrz; t1z = t1z > 0.f ? t1z : NEG_SLOPE * t1z;
    float t1w = a1w + xrw; t1w = t1w > 0.f ? t1w : NEG_SLOPE * t1w;
    float pe0 = t0x * attv.x + t0y * attv.y + t0z * attv.z + t0w * attv.w;
    float pe1 = t1x * attv.x + t1y * attv.y + t1z * attv.z + t1w * attv.w;
    #pragma unroll
    for (int off = 32; off > 0; off >>= 1) {
      pe0 += __shfl_xor(pe0, off, 64);
      pe1 += __shfl_xor(pe1, off, 64);
    }
    float mn = fmaxf(m, fmaxf(pe0, pe1));
    float sc = __expf(m - mn);
    float w0 = __expf(pe0 - mn);
    float w1 = __expf(pe1 - mn);
    d = fmaf(d, sc, w0 + w1);
    ox = fmaf(ox, sc, fmaf(w0, a0x, w1 * a1x));
    oy = fmaf(oy, sc, fmaf(w0, a0y, w1 * a1y));
    oz = fmaf(oz, sc, fmaf(w0, a0z, w1 * a1z));
    ow = fmaf(ow, sc, fmaf(w0, a0w, w1 * a1w));
    m = mn;
  }
  if (p < end) {
    int u0 = col[p];
    ushort4 a04 = *(const ushort4*)&xl[(size_t)u0 * H + f4];
    float a0x = h2f(a04.x), a0y = h2f(a04.y), a0z = h2f(a04.z), a0w = h2f(a04.w);
    float t0x = a0x + xrx; t0x = t0x > 0.f ? t0x : NEG_SLOPE * t0x;
    float t0y = a0y + xry; t0y = t0y > 0.f ? t0y : NEG_SLOPE * t0y;
    float t0z = a0z + xrz; t0z = t0z > 0.f ? t0z : NEG_SLOPE * t0z;
    float t0w = a0w + xrw; t0w = t0w > 0.f ? t0w : NEG_SLOPE * t0w;
    float pe0 = t0x * attv.x + t0y * attv.y + t0z * attv.z + t0w * attv.w;
    pe0 = wave_reduce_sum(pe0);
    float mn = fmaxf(m, pe0);
    float sc = __expf(m - mn);
    float w0 = __expf(pe0 - mn);
    d = fmaf(d, sc, w0);
    ox = fmaf(ox, sc, w0 * a0x);
    oy = fmaf(oy, sc, w0 * a0y);
    oz = fmaf(oz, sc, w0 * a0z);
    ow = fmaf(ow, sc, w0 * a0w);
    m = mn;
  }
  float invd = 1.0f / d;
  float4 bc4 = *(const float4*)&bias_c[f4];
  ox = ox * invd + bc4.x;
  oy = oy * invd + bc4.y;
  oz = oz * invd + bc4.z;
  ow = ow * invd + bc4.w;
  float s = wave_reduce_sum(ox + oy + oz + ow);
  float mean = s * (1.0f / H);
  float cx = ox - mean, cy = oy - mean, cz = oz - mean, cw = ow - mean;
  float sq = wave_reduce_sum(cx * cx + cy * cy + cz * cz + cw * cw);
  float rstd = rsqrtf(sq * (1.0f / H) + LN_EPS);
  float4 g4 = *(const float4*)&ln_g[f4];
  float4 b4 = *(const float4*)&ln_b[f4];
  ushort4 xres4 = *(const ushort4*)&xst[rowbase + f4];
  float yx = fmaxf(fmaf(cx * rstd, g4.x, b4.x), 0.f) + h2f(xres4.x);
  float yy = fmaxf(fmaf(cy * rstd, g4.y, b4.y), 0.f) + h2f(xres4.y);
  float yz = fmaxf(fmaf(cz * rstd, g4.z, b4.z), 0.f) + h2f(xres4.z);
  float yw = fmaxf(fmaf(cw * rstd, g4.w, b4.w), 0.f) + h2f(xres4.w);
  ushort4 yb;
  yb.x = f2h(yx); yb.y = f2h(yy); yb.z = f2h(yz); yb.w = f2h(yw);
  *(ushort4*)&xst[rowbase + f4] = yb;
}

// ---------------- gate init + graph bounds (merged; batch sorted) ----------------
__global__ void gate_init_kernel(float* __restrict__ gate, const float* __restrict__ bg2,
                                 const int* __restrict__ batch,
                                 int* __restrict__ gstart, int* __restrict__ gend) {
  int i = blockIdx.x * 256 + threadIdx.x;
  if (i < N_NODES) {
    gate[i] = bg2[0];
    int b = batch[i];
    if (i == 0 || batch[i - 1] != b) gstart[b] = i;
    if (i == N_NODES - 1 || batch[i + 1] != b) gend[b] = i + 1;
  }
}

// ---------------- pooling: per-graph softmax stats (+ pooled zero) ----------------
__global__ __launch_bounds__(256) void pool_prep_kernel(
    const float* __restrict__ gate, const int* __restrict__ gstart,
    const int* __restrict__ gend, float* __restrict__ gmax, float* __restrict__ gdinv,
    float* __restrict__ pooled)
{
  __shared__ float red[256];
  int g = blockIdx.x, tid = threadIdx.x;
  pooled[(size_t)g * H + tid] = 0.f;
  int s = gstart[g], e = gend[g];
  float lm = -INFINITY;
  for (int i = s + tid; i < e; i += 256) lm = fmaxf(lm, gate[i]);
  red[tid] = lm;
  __syncthreads();
  for (int off = 128; off; off >>= 1) {
    if (tid < off) red[tid] = fmaxf(red[tid], red[tid + off]);
    __syncthreads();
  }
  float m = red[0];
  __syncthreads();
  float lsum = 0.0f;
  for (int i = s + tid; i < e; i += 256) lsum += __expf(gate[i] - m);
  red[tid] = lsum;
  __syncthreads();
  for (int off = 128; off; off >>= 1) {
    if (tid < off) red[tid] += red[tid + off];
    __syncthreads();
  }
  if (tid == 0) {
    gmax[g] = m;
    gdinv[g] = (s < e) ? 1.0f / red[0] : 0.0f;
  }
}

// ---------------- pooling: weighted accumulate (128 nodes per block, fp16 x) ----------------
__global__ __launch_bounds__(256) void pool_accum_kernel(
    const float* __restrict__ gate, const u16* __restrict__ xh,
    const int* __restrict__ batch, const float* __restrict__ gmax,
    const float* __restrict__ gdinv, float* __restrict__ pooled)
{
  __shared__ float wl[128];
  __shared__ int gl[128];
  int b0 = blockIdx.x * 128;
  int tid = threadIdx.x;
  if (tid < 128) {
    int v = b0 + tid;
    if (v < N_NODES) {
      int g = batch[v];
      gl[tid] = g;
      wl[tid] = __expf(gate[v] - gmax[g]) * gdinv[g];
    } else {
      gl[tid] = -1;
      wl[tid] = 0.f;
    }
  }
  __syncthreads();
  int cnt = min(128, N_NODES - b0);
  float acc = 0.f;
  int cur = gl[0];
  for (int j = 0; j < cnt; j++) {
    int g = gl[j];
    if (g != cur) {
      atomicAdd(&pooled[(size_t)cur * H + tid], acc);
      acc = 0.f;
      cur = g;
    }
    acc += wl[j] * h2f(xh[(size_t)(b0 + j) * H + tid]);
  }
  if (cur >= 0) atomicAdd(&pooled[(size_t)cur * H + tid], acc);
}

// ---------------- fused head: pooled -> z -> {cls, r1} -> residual ----------------
__global__ __launch_bounds__(256) void head_kernel(
    const float* __restrict__ pooled,
    const float* __restrict__ Ws, const float* __restrict__ bs,
    const float* __restrict__ Wc, const float* __restrict__ bc,
    const float* __restrict__ Wr1, const float* __restrict__ br1,
    const float* __restrict__ Wr2, const float* __restrict__ br2,
    float* __restrict__ out)
{
  __shared__ float psh[256];
  __shared__ float zsh[256];
  __shared__ float r1sh[128];
  int g = blockIdx.x, tid = threadIdx.x;
  psh[tid] = pooled[(size_t)g * H + tid];
  __syncthreads();
  {
    float acc = bs[tid];
    const float4* wr = (const float4*)&Ws[(size_t)tid * H];
    for (int k4 = 0; k4 < H / 4; k4++) {
      float4 wv = wr[k4];
      float4 av = *(const float4*)&psh[k4 * 4];
      acc += av.x * wv.x + av.y * wv.y + av.z * wv.z + av.w * wv.w;
    }
    zsh[tid] = fmaxf(acc, 0.f);
  }
  __syncthreads();
  if (tid < NB) {
    float acc = bc[tid];
    const float4* wr = (const float4*)&Wc[(size_t)tid * H];
    for (int k4 = 0; k4 < H / 4; k4++) {
      float4 wv = wr[k4];
      float4 av = *(const float4*)&zsh[k4 * 4];
      acc += av.x * wv.x + av.y * wv.y + av.z * wv.z + av.w * wv.w;
    }
    out[(size_t)g * NB + tid] = acc;
  }
  if (tid < 128) {
    float acc = br1[tid];
    const float4* wr = (const float4*)&Wr1[(size_t)tid * H];
    for (int k4 = 0; k4 < H / 4; k4++) {
      float4 wv = wr[k4];
      float4 av = *(const float4*)&zsh[k4 * 4];
      acc += av.x * wv.x + av.y * wv.y + av.z * wv.z + av.w * wv.w;
    }
    r1sh[tid] = fmaxf(acc, 0.f);
  }
  __syncthreads();
  if (tid < 64) {
    float s2 = r1sh[tid] * Wr2[tid] + r1sh[tid + 64] * Wr2[tid + 64];
    s2 = wave_reduce_sum(s2);
    if (tid == 0) out[(size_t)NGRAPH * NB + g] = tanhf(s2 + br2[0]);
  }
}

// ---------------- launcher ----------------
extern "C" void kernel_launch(void* const* d_in, const int* in_sizes, int n_in,
                              void* d_out, int out_size, void* d_ws, size_t ws_size,
                              hipStream_t stream) {
  const float* x_in   = (const float*)d_in[0];
  const int*   eidx   = (const int*)d_in[1];
  const int*   batch  = (const int*)d_in[2];
  const float* W_in   = (const float*)d_in[3];
  const float* b_in   = (const float*)d_in[4];
  const float* Wl     = (const float*)d_in[5];
  const float* bl     = (const float*)d_in[6];
  const float* Wr     = (const float*)d_in[7];
  const float* br     = (const float*)d_in[8];
  const float* att    = (const float*)d_in[9];
  const float* bias_c = (const float*)d_in[10];
  const float* ln_g   = (const float*)d_in[11];
  const float* ln_b   = (const float*)d_in[12];
  const float* Wg1    = (const float*)d_in[13];
  const float* bg1    = (const float*)d_in[14];
  const float* Wg2    = (const float*)d_in[15];
  const float* bg2    = (const float*)d_in[16];
  const float* Ws     = (const float*)d_in[17];
  const float* bs     = (const float*)d_in[18];
  const float* Wc     = (const float*)d_in[19];
  const float* bc     = (const float*)d_in[20];
  const float* Wr1    = (const float*)d_in[21];
  const float* br1    = (const float*)d_in[22];
  const float* Wr2    = (const float*)d_in[23];
  const float* br2    = (const float*)d_in[24];
  float* out = (float*)d_out;

  char* w = (char*)d_ws;
  u16* x_h    = (u16*)w;    w += sizeof(u16) * (size_t)N_NODES * H;
  u16* xl_h   = (u16*)w;    w += sizeof(u16) * (size_t)N_NODES * H;
  u16* xr_h   = (u16*)w;    w += sizeof(u16) * (size_t)N_NODES * H;
  u16* xin_h  = (u16*)w;    w += sizeof(u16) * (size_t)N_NODES * IN_DIM;
  u16* win_h  = (u16*)w;    w += sizeof(u16) * (size_t)H * IN_DIM;
  u16* wl_h   = (u16*)w;    w += sizeof(u16) * (size_t)LAYERS * H * H;
  u16* wr_h   = (u16*)w;    w += sizeof(u16) * (size_t)LAYERS * H * H;
  u16* wg1_h  = (u16*)w;    w += sizeof(u16) * (size_t)H * H;
  float* pooled = (float*)w; w += sizeof(float) * NGRAPH * H;
  float* gate = (float*)w;  w += sizeof(float) * N_NODES;
  float* gmax = (float*)w;  w += sizeof(float) * NGRAPH;
  float* gdinv= (float*)w;  w += sizeof(float) * NGRAPH;
  int* cnt    = (int*)w;    w += sizeof(int) * N_NODES;
  int* rowp   = (int*)w;    w += sizeof(int) * (N_NODES + 1);
  int* col    = (int*)w;    w += sizeof(int) * EE;
  int* partial= (int*)w;    w += sizeof(int) * N_NODES;
  int* bsums  = (int*)w;    w += sizeof(int) * 256;
  int* gstart = (int*)w;    w += sizeof(int) * NGRAPH;
  int* gend   = (int*)w;    w += sizeof(int) * NGRAPH;
  (void)ws_size; (void)n_in; (void)in_sizes; (void)out_size;

  const int* src = eidx;
  const int* dst = eidx + N_EDGES;
  int nblkN = (N_NODES + 255) / 256;
  int nblkE = (N_EDGES + 255) / 256;
  int mtiles = (N_NODES + GTM - 1) / GTM;
  int mtiles2 = (N_NODES + DTM - 1) / DTM;

  // CSR build (by dst, self-loops included)
  init_counts_kernel<<<nblkN, 256, 0, stream>>>(cnt);
  count_edges_kernel<<<nblkE, 256, 0, stream>>>(dst, cnt);
  scan_blocks_kernel<<<nblkN, 256, 0, stream>>>(cnt, partial, bsums, N_NODES);
  scan_sums_kernel<<<1, 256, 0, stream>>>(bsums, nblkN);
  scan_write_kernel<<<nblkN, 256, 0, stream>>>(partial, bsums, rowp, N_NODES);
  fill_self_kernel<<<nblkN, 256, 0, stream>>>(rowp, col, cnt);
  fill_edges_kernel<<<nblkE, 256, 0, stream>>>(src, dst, cnt, col);

  // casts
  {
    int maxn4 = LAYERS * H * H / 4;
    dim3 gcast((maxn4 + 255) / 256, 4);
    cast_weights_kernel<<<gcast, 256, 0, stream>>>(W_in, Wg1, Wl, Wr,
                                                   win_h, wg1_h, wl_h, wr_h);
    int n4 = N_NODES * IN_DIM / 4;
    cast_f16_kernel<<<(n4 + 255) / 256, 256, 0, stream>>>(x_in, xin_h, n4);
  }

  // input projection -> x_h
  dim3 gproj(2, mtiles);
  gemm_proj_kernel<<<gproj, 256, 0, stream>>>(xin_h, win_h, b_in, x_h, N_NODES, IN_DIM);

  int nblkV = N_NODES / 4;
  for (int l = 0; l < LAYERS; l++) {
    gemm_dual2_kernel<<<mtiles2, 256, 0, stream>>>(x_h,
        wl_h + (size_t)l * H * H, wr_h + (size_t)l * H * H,
        bl + l * H, br + l * H, xl_h, xr_h, N_NODES);
    layer_fused_kernel<<<nblkV, 256, 0, stream>>>(xl_h, xr_h, x_h, rowp, col,
        att + l * H, bias_c + l * H, ln_g + l * H, ln_b + l * H);
  }

  // gate (fused GEMM + row-dot); gate_init also computes graph bounds
  gate_init_kernel<<<nblkN, 256, 0, stream>>>(gate, bg2, batch, gstart, gend);
  dim3 ggate(2, mtiles);
  gemm_gate_kernel<<<ggate, 256, 0, stream>>>(x_h, wg1_h, bg1, Wg2, gate, N_NODES);

  // pooling
  pool_prep_kernel<<<NGRAPH, 256, 0, stream>>>(gate, gstart, gend, gmax, gdinv, pooled);
  pool_accum_kernel<<<(N_NODES + 127) / 128, 256, 0, stream>>>(gate, x_h, batch, gmax, gdinv, pooled);

  // fused heads
  head_kernel<<<NGRAPH, 256, 0, stream>>>(pooled, Ws, bs, Wc, bc, Wr1, br1, Wr2, br2, out);
}